// Round 8
// baseline (179.121 us; speedup 1.0000x reference)
//
#include <hip/hip_runtime.h>
#include <hip/hip_bf16.h>
#include <math.h>

typedef __attribute__((ext_vector_type(8))) __bf16 bf16x8;
typedef __attribute__((ext_vector_type(4))) float f32x4;

#define S_LEN 1024
#define D_MODEL 384
#define BATCH 32
#define N3 1152
#define KVB 32
#define NT (S_LEN / KVB)

#define MFMA16(a, b, c) __builtin_amdgcn_mfma_f32_16x16x32_bf16((a), (b), (c), 0, 0, 0)

static __device__ __forceinline__ ushort f2bf(float f) {
    __bf16 h = (__bf16)f;
    return __builtin_bit_cast(ushort, h);
}
static __device__ __forceinline__ uint pk2(float a, float b) {
    return (uint)f2bf(a) | ((uint)f2bf(b) << 16);
}

// ---------------- kernel 1: positional-encoding table, transposed peT[k][s] ----
__global__ void pe_kernel(float* peT) {
    int idx = blockIdx.x * 256 + threadIdx.x;      // 384*1024 total
    int k = idx >> 10, s = idx & 1023;
    float e = -(float)((k >> 1) * 2) * (logf(10000.0f) / (float)D_MODEL);
    float div = expf(e);
    float a = (float)s * div;
    peT[idx] = (k & 1) ? cosf(a) : sinf(a);
}

// ---------------- kernel 2: W [384][1152] f32 -> Wt [1152][384] bf16 ----------
__global__ void wt_kernel(const float* __restrict__ W, ushort* __restrict__ Wt) {
    __shared__ float tile[32][33];
    int n0 = blockIdx.x * 32, k0 = blockIdx.y * 32;
    int tx = threadIdx.x, ty = threadIdx.y;
#pragma unroll
    for (int r = 0; r < 4; ++r) {
        int kl = ty * 4 + r;
        tile[kl][tx] = W[(size_t)(k0 + kl) * N3 + n0 + tx];
    }
    __syncthreads();
#pragma unroll
    for (int r = 0; r < 4; ++r) {
        int nl = ty * 4 + r;
        Wt[(size_t)(n0 + nl) * D_MODEL + k0 + tx] = f2bf(tile[tx][nl]);
    }
}

// ---------------- kernel 3: A[m][k] = bf16(x[b][k][s] + peT[k][s]) ------------
__global__ void astage_kernel(const float* __restrict__ x, const float* __restrict__ peT,
                              ushort* __restrict__ A) {
    __shared__ float tile[32][33];
    int s0 = blockIdx.x * 32, k0 = blockIdx.y * 32, b = blockIdx.z;
    int tx = threadIdx.x, ty = threadIdx.y;
#pragma unroll
    for (int r = 0; r < 4; ++r) {
        int kl = ty * 4 + r;
        tile[kl][tx] = x[(size_t)(b * D_MODEL + k0 + kl) * S_LEN + s0 + tx]
                     + peT[(size_t)(k0 + kl) * S_LEN + s0 + tx];
    }
    __syncthreads();
#pragma unroll
    for (int r = 0; r < 4; ++r) {
        int sl = ty * 4 + r;
        A[(size_t)(b * S_LEN + s0 + sl) * D_MODEL + k0 + tx] = f2bf(tile[tx][sl]);
    }
}

// ---------------- kernel 4: qkv GEMM; V-range blocks write transposed Vt -----
__global__ __launch_bounds__(256) void qkv_gemm(const ushort* __restrict__ A,
                                                const ushort* __restrict__ Wt,
                                                const float* __restrict__ bias,
                                                ushort* __restrict__ qkv,
                                                ushort* __restrict__ Vt) {
    __shared__ __align__(16) ushort As[128 * 32];
    __shared__ __align__(16) ushort Bs[128 * 32];
    int id = blockIdx.x;                  // 2304 = 8 chunks * (9 n * 32 m)
    int g = id / 288, loc = id % 288;
    int nt_ = loc / 32, mt_ = g * 32 + (loc % 32);
    int m0 = mt_ * 128, n0 = nt_ * 128;
    int tid = threadIdx.x;
    int wave = tid >> 6, lane = tid & 63;
    int i16 = lane & 15, gq = lane >> 4;
    int wr = wave >> 1, wc = wave & 1;
    f32x4 acc[4][4] = {};
    for (int ks = 0; ks < 12; ++ks) {
        int k0 = ks * 32;
        __syncthreads();
#pragma unroll
        for (int i = 0; i < 2; ++i) {
            int off = (wave * 2 + i) * 1024;
            int row = (off >> 6) + (lane >> 2);
            int kc = lane & 3;
            const ushort* ga = A + (size_t)(m0 + row) * D_MODEL + k0 + kc * 8;
            __builtin_amdgcn_global_load_lds(
                (const __attribute__((address_space(1))) uint32_t*)ga,
                (__attribute__((address_space(3))) uint32_t*)((char*)As + off), 16, 0, 0);
            const ushort* gb = Wt + (size_t)(n0 + row) * D_MODEL + k0 + kc * 8;
            __builtin_amdgcn_global_load_lds(
                (const __attribute__((address_space(1))) uint32_t*)gb,
                (__attribute__((address_space(3))) uint32_t*)((char*)Bs + off), 16, 0, 0);
        }
        __syncthreads();
        bf16x8 af[4], bfr[4];
#pragma unroll
        for (int mt = 0; mt < 4; ++mt) {
            int row = wr * 64 + mt * 16 + i16;
            af[mt] = *reinterpret_cast<const bf16x8*>(&As[row * 32 + gq * 8]);
        }
#pragma unroll
        for (int nt = 0; nt < 4; ++nt) {
            int row = wc * 64 + nt * 16 + i16;
            bfr[nt] = *reinterpret_cast<const bf16x8*>(&Bs[row * 32 + gq * 8]);
        }
#pragma unroll
        for (int mt = 0; mt < 4; ++mt)
#pragma unroll
            for (int nt = 0; nt < 4; ++nt)
                acc[mt][nt] = MFMA16(af[mt], bfr[nt], acc[mt][nt]);
    }
    if (n0 < 2 * D_MODEL) {
#pragma unroll
        for (int nt = 0; nt < 4; ++nt) {
            int n = n0 + wc * 64 + nt * 16 + i16;
            float bv = bias[n];
#pragma unroll
            for (int mt = 0; mt < 4; ++mt)
#pragma unroll
                for (int r = 0; r < 4; ++r) {
                    int m = m0 + wr * 64 + mt * 16 + gq * 4 + r;
                    qkv[(size_t)m * N3 + n] = f2bf(acc[mt][nt][r] + bv);
                }
        }
    } else {
        // V range: write transposed Vt[b][c][s] directly (vtrans fused)
        int b = m0 >> 10;
        int s_base = (m0 & 1023) + wr * 64;
#pragma unroll
        for (int nt = 0; nt < 4; ++nt) {
            int n = n0 + wc * 64 + nt * 16 + i16;
            float bv = bias[n];
            int c = n - 2 * D_MODEL;
            ushort* vrow = Vt + (size_t)(b * D_MODEL + c) * S_LEN;
#pragma unroll
            for (int mt = 0; mt < 4; ++mt) {
                int s = s_base + mt * 16 + gq * 4;
                ushort4 p4;
                p4.x = f2bf(acc[mt][nt][0] + bv);
                p4.y = f2bf(acc[mt][nt][1] + bv);
                p4.z = f2bf(acc[mt][nt][2] + bv);
                p4.w = f2bf(acc[mt][nt][3] + bv);
                *reinterpret_cast<ushort4*>(vrow + s) = p4;
            }
        }
    }
}

// ---------------- kernel 5: flash attention v8 (v7 bugfixed) -----------------
// (1) Conflict-free LDS layouts: K [kt][gq][32j][16B], V [ct][gq][16c][16B],
//     P [jc][32q][16B] (jc stride 512 B — v7's 1024 B stride overflowed the
//     2 KB per-qg buffer and cross-contaminated q-groups).
// (2) Counted vmcnt: V double-buffered, K single. K(t+1)+V(t+1) issued after
//     B2; loop-top waits vmcnt(6) lgkmcnt(0) (K ready, V in flight; lgkm drain
//     closes the P WAR race that B3 used to cover). B2 waits vmcnt(0) (V(t)
//     issued a full tile ago - near-free). 2 barriers/tile.
__global__ __launch_bounds__(256, 2) void attn_kernel(const ushort* __restrict__ qkv,
                                                      const ushort* __restrict__ Vt,
                                                      float* __restrict__ out) {
    __shared__ __align__(16) ushort Ks[12 * 4 * 32 * 8];      // 24 KB
    __shared__ __align__(16) ushort Vts[2][24 * 4 * 16 * 8];  // 2 x 24 KB
    __shared__ __align__(16) ushort Pq[2][4 * 32 * 8];        // 2 x 2 KB
    __shared__ float Ltab[2][2][2][16];                       // [qg][h][qh][i16]
    int id = blockIdx.x;                                   // 512 = 16 qt * 4 slot * 8 xcd
    int xcd = id & 7, slot = (id >> 3) & 3, qt = id >> 5;
    int b = slot * 8 + xcd;                                // batch grouped per XCD
    int tid = threadIdx.x;
    int wave = tid >> 6, lane = tid & 63;
    int i16 = lane & 15, gq = lane >> 4;
    int qg = wave & 1, h = wave >> 1;
    int q0w = qt * 64 + qg * 32;

    const ushort* Kbase = qkv + (size_t)b * S_LEN * N3 + D_MODEL;
    const ushort* Vbase = Vt + (size_t)b * D_MODEL * S_LEN;
    int l31 = lane & 31, l5 = lane >> 5;
    int l15 = lane & 15, l4 = lane >> 4;

    // K: 24 x 1KB chunks (6/wave). Chunk ii = [kt = ii>>1][gq-pair half = ii&1].
    // lane l -> LDS byte ii*1024 + l*16 == K[kt][gq = half*2+(l>>5)][j = l&31]
    auto stage_K = [&](int kv0) {
#pragma unroll
        for (int r = 0; r < 6; ++r) {
            int ii = wave * 6 + r;
            int kt = ii >> 1, half = ii & 1;
            const ushort* ga = Kbase + (size_t)(kv0 + l31) * N3 + kt * 32 + (half * 2 + l5) * 8;
            __builtin_amdgcn_global_load_lds(
                (const __attribute__((address_space(1))) uint32_t*)ga,
                (__attribute__((address_space(3))) uint32_t*)((char*)Ks + ii * 1024), 16, 0, 0);
        }
    };
    // V: 24 x 1KB chunks (6/wave), chunk ii = ct. lane l -> V[ct][gq=l>>4][c=l&15]
    auto stage_V = [&](int kv0, int bi) {
#pragma unroll
        for (int r = 0; r < 6; ++r) {
            int ii = wave * 6 + r;
            const ushort* ga = Vbase + (size_t)(ii * 16 + l15) * S_LEN + kv0 + l4 * 8;
            __builtin_amdgcn_global_load_lds(
                (const __attribute__((address_space(1))) uint32_t*)ga,
                (__attribute__((address_space(3))) uint32_t*)((char*)&Vts[bi][0] + ii * 1024), 16, 0, 0);
        }
    };

    stage_K(0);
    stage_V(0, 0);

    // Q fragments (B-operand): lane (gq,i16): Q[q0w + qh*16 + i16][kt*32+gq*8..+8]
    bf16x8 qf[12][2];
    const ushort* Qb0 = qkv + (size_t)(b * S_LEN + q0w + i16) * N3;
    const ushort* Qb1 = qkv + (size_t)(b * S_LEN + q0w + 16 + i16) * N3;
#pragma unroll
    for (int kt = 0; kt < 12; ++kt) {
        qf[kt][0] = *reinterpret_cast<const bf16x8*>(Qb0 + kt * 32 + gq * 8);
        qf[kt][1] = *reinterpret_cast<const bf16x8*>(Qb1 + kt * 32 + gq * 8);
    }

    f32x4 oc[12][2] = {};
    float lsum0 = 0.f, lsum1 = 0.f;
    const float sl2e = 0.05103103630798287f * 1.4426950408889634f;

    char* PqB = (char*)&Pq[qg][0];
    const int kread = gq * 512 + (h * 16 + i16) * 16;     // K frag byte (per kt*2048)
    const int vread = gq * 256 + i16 * 16;                // V frag byte (per ct*1024)

    for (int t = 0; t < NT; ++t) {
        // K(t) landed (my 6 oldest); V(t) may still be in flight.
        // lgkmcnt(0): my ds ops (incl. P reads of t-1) done before the barrier
        // -> no WAR on P / K when the next phases write them.
        asm volatile("s_waitcnt vmcnt(6) lgkmcnt(0)" ::: "memory");
        __builtin_amdgcn_s_barrier();                      // B1: K(t) ready block-wide
        __builtin_amdgcn_sched_barrier(0);

        // ---- QK: S[h*16..+16 j][32 q] ----
        const char* Kb = (const char*)Ks;
        f32x4 sacc0 = {}, sacc1 = {};
        __builtin_amdgcn_s_setprio(1);
#pragma unroll
        for (int kt = 0; kt < 12; ++kt) {
            bf16x8 kf = *reinterpret_cast<const bf16x8*>(Kb + kt * 2048 + kread);
            sacc0 = MFMA16(kf, qf[kt][0], sacc0);
            sacc1 = MFMA16(kf, qf[kt][1], sacc1);
        }
        __builtin_amdgcn_s_setprio(0);

        // ---- p = exp2(s*scale*log2e) (drop-max), accumulate l, write P ----
        float p00 = exp2f(sacc0[0] * sl2e), p01 = exp2f(sacc0[1] * sl2e);
        float p02 = exp2f(sacc0[2] * sl2e), p03 = exp2f(sacc0[3] * sl2e);
        float p10 = exp2f(sacc1[0] * sl2e), p11 = exp2f(sacc1[1] * sl2e);
        float p12 = exp2f(sacc1[2] * sl2e), p13 = exp2f(sacc1[3] * sl2e);
        lsum0 += (p00 + p01) + (p02 + p03);
        lsum1 += (p10 + p11) + (p12 + p13);
        {
            // P[j = h*16+gq*4+r][q = qh*16+i16] -> byte jc*512 + q*16 + jl*2,
            // jc = h*2+(gq>>1), jl = (gq&1)*4 + r
            int pw = (h * 2 + (gq >> 1)) * 512 + (gq & 1) * 8;
            uint2 w0; w0.x = pk2(p00, p01); w0.y = pk2(p02, p03);
            uint2 w1; w1.x = pk2(p10, p11); w1.y = pk2(p12, p13);
            *reinterpret_cast<uint2*>(PqB + pw + i16 * 16) = w0;
            *reinterpret_cast<uint2*>(PqB + pw + (16 + i16) * 16) = w1;
        }
        // P visible + V(t) landed (issued a full tile ago -> near-free drain)
        asm volatile("s_waitcnt vmcnt(0) lgkmcnt(0)" ::: "memory");
        __builtin_amdgcn_s_barrier();                      // B2
        __builtin_amdgcn_sched_barrier(0);
        if (t + 1 < NT) {                                  // prefetch: never drained mid-tile
            stage_K((t + 1) * KVB);
            stage_V((t + 1) * KVB, (t + 1) & 1);
        }

        // ---- PV: O[h*192..+192 c][32 q] += V-half . P ----
        // P B-frag: lane (gq,i16): P[j = gq*8 + e][q = qh*16 + i16]
        bf16x8 pf0 = *reinterpret_cast<const bf16x8*>(PqB + gq * 512 + i16 * 16);
        bf16x8 pf1 = *reinterpret_cast<const bf16x8*>(PqB + gq * 512 + (16 + i16) * 16);
        const char* Vb = (const char*)&Vts[t & 1][0];
        __builtin_amdgcn_s_setprio(1);
#pragma unroll
        for (int ct = 0; ct < 12; ++ct) {
            bf16x8 vf = *reinterpret_cast<const bf16x8*>(Vb + (h * 12 + ct) * 1024 + vread);
            oc[ct][0] = MFMA16(vf, pf0, oc[ct][0]);
            oc[ct][1] = MFMA16(vf, pf1, oc[ct][1]);
        }
        __builtin_amdgcn_s_setprio(0);
        // no B3: K(t+1) safe (K ds_reads drained at B2), V(t+1) -> other buffer,
        // P(t+1) written only after B1(t+1) (lgkm-drained + barrier).
    }

    // ---- l: reduce over gq (this wave's j-half), then cross-half via LDS ----
    lsum0 += __shfl_xor(lsum0, 16); lsum0 += __shfl_xor(lsum0, 32);
    lsum1 += __shfl_xor(lsum1, 16); lsum1 += __shfl_xor(lsum1, 32);
    __syncthreads();
    if (gq == 0) {
        Ltab[qg][h][0][i16] = lsum0;
        Ltab[qg][h][1][i16] = lsum1;
    }
    __syncthreads();
    float inv0 = 1.0f / (Ltab[qg][0][0][i16] + Ltab[qg][1][0][i16]);
    float inv1 = 1.0f / (Ltab[qg][0][1][i16] + Ltab[qg][1][1][i16]);

    // ---- store O: c = h*192 + ct*16 + gq*4 + r, q = q0w + qh*16 + i16 ----
    float* obase = out + (size_t)b * D_MODEL * S_LEN + q0w + i16;
#pragma unroll
    for (int ct = 0; ct < 12; ++ct)
#pragma unroll
        for (int r = 0; r < 4; ++r) {
            int c = h * 192 + ct * 16 + gq * 4 + r;
            obase[(size_t)c * S_LEN] = oc[ct][0][r] * inv0;
            obase[(size_t)c * S_LEN + 16] = oc[ct][1][r] * inv1;
        }
}

extern "C" void kernel_launch(void* const* d_in, const int* in_sizes, int n_in,
                              void* d_out, int out_size, void* d_ws, size_t ws_size,
                              hipStream_t stream) {
    const float* x    = (const float*)d_in[0];
    const float* W    = (const float*)d_in[1];
    const float* bias = (const float*)d_in[2];
    float* out = (float*)d_out;

    char* ws = (char*)d_ws;
    ushort* A_bf  = (ushort*)(ws);                                  // 25,165,824
    ushort* Wt    = (ushort*)(ws + 25165824);                       //    884,736
    float*  peT   = (float*)(ws + 26050560);                        //  1,572,864
    ushort* qkv   = (ushort*)(ws + 27623424);                       // 75,497,472
    ushort* Vt    = (ushort*)(ws + 103120896);                      // 25,165,824

    pe_kernel<<<1536, 256, 0, stream>>>(peT);
    wt_kernel<<<dim3(36, 12), dim3(32, 8), 0, stream>>>(W, Wt);
    astage_kernel<<<dim3(32, 12, 32), dim3(32, 8), 0, stream>>>(x, peT, A_bf);
    qkv_gemm<<<2304, 256, 0, stream>>>(A_bf, Wt, bias, qkv, Vt);
    attn_kernel<<<512, 256, 0, stream>>>(qkv, Vt, out);
}

// Round 9
// 154.966 us; speedup vs baseline: 1.1559x; 1.1559x over previous
//
#include <hip/hip_runtime.h>
#include <hip/hip_bf16.h>
#include <math.h>

typedef __attribute__((ext_vector_type(8))) __bf16 bf16x8;
typedef __attribute__((ext_vector_type(4))) float f32x4;

#define S_LEN 1024
#define D_MODEL 384
#define BATCH 32
#define N3 1152
#define KVB 32
#define NT (S_LEN / KVB)

#define MFMA16(a, b, c) __builtin_amdgcn_mfma_f32_16x16x32_bf16((a), (b), (c), 0, 0, 0)

static __device__ __forceinline__ ushort f2bf(float f) {
    __bf16 h = (__bf16)f;
    return __builtin_bit_cast(ushort, h);
}
static __device__ __forceinline__ uint pk2(float a, float b) {
    return (uint)f2bf(a) | ((uint)f2bf(b) << 16);
}

// ---------------- kernel 1: positional-encoding table, transposed peT[k][s] ----
__global__ void pe_kernel(float* peT) {
    int idx = blockIdx.x * 256 + threadIdx.x;      // 384*1024 total
    int k = idx >> 10, s = idx & 1023;
    float e = -(float)((k >> 1) * 2) * (logf(10000.0f) / (float)D_MODEL);
    float div = expf(e);
    float a = (float)s * div;
    peT[idx] = (k & 1) ? cosf(a) : sinf(a);
}

// ---------------- kernel 2: W [384][1152] f32 -> Wt [1152][384] bf16 ----------
__global__ void wt_kernel(const float* __restrict__ W, ushort* __restrict__ Wt) {
    __shared__ float tile[32][33];
    int n0 = blockIdx.x * 32, k0 = blockIdx.y * 32;
    int tx = threadIdx.x, ty = threadIdx.y;
#pragma unroll
    for (int r = 0; r < 4; ++r) {
        int kl = ty * 4 + r;
        tile[kl][tx] = W[(size_t)(k0 + kl) * N3 + n0 + tx];
    }
    __syncthreads();
#pragma unroll
    for (int r = 0; r < 4; ++r) {
        int nl = ty * 4 + r;
        Wt[(size_t)(n0 + nl) * D_MODEL + k0 + tx] = f2bf(tile[tx][nl]);
    }
}

// ---------------- kernel 3: A[m][k] = bf16(x[b][k][s] + peT[k][s]) ------------
__global__ void astage_kernel(const float* __restrict__ x, const float* __restrict__ peT,
                              ushort* __restrict__ A) {
    __shared__ float tile[32][33];
    int s0 = blockIdx.x * 32, k0 = blockIdx.y * 32, b = blockIdx.z;
    int tx = threadIdx.x, ty = threadIdx.y;
#pragma unroll
    for (int r = 0; r < 4; ++r) {
        int kl = ty * 4 + r;
        tile[kl][tx] = x[(size_t)(b * D_MODEL + k0 + kl) * S_LEN + s0 + tx]
                     + peT[(size_t)(k0 + kl) * S_LEN + s0 + tx];
    }
    __syncthreads();
#pragma unroll
    for (int r = 0; r < 4; ++r) {
        int sl = ty * 4 + r;
        A[(size_t)(b * S_LEN + s0 + sl) * D_MODEL + k0 + tx] = f2bf(tile[tx][sl]);
    }
}

// ---------------- kernel 4: qkv GEMM -> Q rows + pre-tiled/swizzled K,V panels
// K_tiled[b][t][j 32][384k], row 768B, col 16B-slot XOR (k>>3)^(j&7) baked in.
// V_tiled[b][t][c 384][j 32], row 64B,  col 16B-slot XOR (j>>3)^((c>>1)&3).
// Panels are 24 KB contiguous -> attn staging is a linear coalesced memcpy.
__global__ __launch_bounds__(256) void qkv_gemm(const ushort* __restrict__ A,
                                                const ushort* __restrict__ Wt,
                                                const float* __restrict__ bias,
                                                ushort* __restrict__ Qb,
                                                ushort* __restrict__ Ktl,
                                                ushort* __restrict__ Vtl) {
    __shared__ __align__(16) ushort As[128 * 32];
    __shared__ __align__(16) ushort Bs[128 * 32];
    int id = blockIdx.x;                  // 2304 = 8 chunks * (9 n * 32 m)
    int g = id / 288, loc = id % 288;
    int nt_ = loc / 32, mt_ = g * 32 + (loc % 32);
    int m0 = mt_ * 128, n0 = nt_ * 128;
    int tid = threadIdx.x;
    int wave = tid >> 6, lane = tid & 63;
    int i16 = lane & 15, gq = lane >> 4;
    int wr = wave >> 1, wc = wave & 1;
    f32x4 acc[4][4] = {};
    for (int ks = 0; ks < 12; ++ks) {
        int k0 = ks * 32;
        __syncthreads();
#pragma unroll
        for (int i = 0; i < 2; ++i) {
            int off = (wave * 2 + i) * 1024;
            int row = (off >> 6) + (lane >> 2);
            int kc = lane & 3;
            const ushort* ga = A + (size_t)(m0 + row) * D_MODEL + k0 + kc * 8;
            __builtin_amdgcn_global_load_lds(
                (const __attribute__((address_space(1))) uint32_t*)ga,
                (__attribute__((address_space(3))) uint32_t*)((char*)As + off), 16, 0, 0);
            const ushort* gb = Wt + (size_t)(n0 + row) * D_MODEL + k0 + kc * 8;
            __builtin_amdgcn_global_load_lds(
                (const __attribute__((address_space(1))) uint32_t*)gb,
                (__attribute__((address_space(3))) uint32_t*)((char*)Bs + off), 16, 0, 0);
        }
        __syncthreads();
        bf16x8 af[4], bfr[4];
#pragma unroll
        for (int mt = 0; mt < 4; ++mt) {
            int row = wr * 64 + mt * 16 + i16;
            af[mt] = *reinterpret_cast<const bf16x8*>(&As[row * 32 + gq * 8]);
        }
#pragma unroll
        for (int nt = 0; nt < 4; ++nt) {
            int row = wc * 64 + nt * 16 + i16;
            bfr[nt] = *reinterpret_cast<const bf16x8*>(&Bs[row * 32 + gq * 8]);
        }
#pragma unroll
        for (int mt = 0; mt < 4; ++mt)
#pragma unroll
            for (int nt = 0; nt < 4; ++nt)
                acc[mt][nt] = MFMA16(af[mt], bfr[nt], acc[mt][nt]);
    }
    if (n0 < D_MODEL) {
        // Q range: compact rows Qb[m][0..384)
#pragma unroll
        for (int nt = 0; nt < 4; ++nt) {
            int n = n0 + wc * 64 + nt * 16 + i16;
            float bv = bias[n];
#pragma unroll
            for (int mt = 0; mt < 4; ++mt)
#pragma unroll
                for (int r = 0; r < 4; ++r) {
                    int m = m0 + wr * 64 + mt * 16 + gq * 4 + r;
                    Qb[(size_t)m * D_MODEL + n] = f2bf(acc[mt][nt][r] + bv);
                }
        }
    } else if (n0 < 2 * D_MODEL) {
        // K range -> K_tiled panel, swizzle baked
        int b = m0 >> 10;
#pragma unroll
        for (int nt = 0; nt < 4; ++nt) {
            int n = n0 + wc * 64 + nt * 16 + i16;
            float bv = bias[n];
            int k2 = n - D_MODEL;                 // 0..383
            int slotx = k2 >> 3, within = k2 & 7;
#pragma unroll
            for (int mt = 0; mt < 4; ++mt)
#pragma unroll
                for (int r = 0; r < 4; ++r) {
                    int m = m0 + wr * 64 + mt * 16 + gq * 4 + r;
                    int s = m & 1023;
                    int t = s >> 5, j = s & 31;
                    size_t idx = (size_t)(b * 32 + t) * 12288 + j * 384
                               + (((slotx ^ (j & 7)) << 3) + within);
                    Ktl[idx] = f2bf(acc[mt][nt][r] + bv);
                }
        }
    } else {
        // V range -> V_tiled panel, swizzle baked (4 consecutive s per ushort4)
        int b = m0 >> 10;
#pragma unroll
        for (int nt = 0; nt < 4; ++nt) {
            int n = n0 + wc * 64 + nt * 16 + i16;
            float bv = bias[n];
            int c = n - 2 * D_MODEL;
            int cx = (c >> 1) & 3;
#pragma unroll
            for (int mt = 0; mt < 4; ++mt) {
                int m = m0 + wr * 64 + mt * 16 + gq * 4;
                int s = m & 1023;
                int t = s >> 5, j = s & 31;       // j % 4 == 0
                size_t idx = (size_t)(b * 32 + t) * 12288 + c * 32
                           + ((((j >> 3) ^ cx) << 3) + (j & 7));
                ushort4 p4;
                p4.x = f2bf(acc[mt][nt][0] + bv);
                p4.y = f2bf(acc[mt][nt][1] + bv);
                p4.z = f2bf(acc[mt][nt][2] + bv);
                p4.w = f2bf(acc[mt][nt][3] + bv);
                *reinterpret_cast<ushort4*>(&Vtl[idx]) = p4;
            }
        }
    }
}

// ---------------- kernel 5: flash attention v9 -------------------------------
// v8 schedule (counted vmcnt(6), V-dbuf, 2 barriers, setprio, 2 blocks/CU) with
// COALESCED staging: K/V panels are pre-tiled+pre-swizzled in global (by the
// GEMM epilogue), so each global_load_lds chunk is a linear 1KB span (lane*16B
// contiguous, 16 cachelines). Fragment reads apply the matching 16B-slot XOR:
// verified 2-way (free) bank pattern on both K and V.
__global__ __launch_bounds__(256, 2) void attn_kernel(const ushort* __restrict__ Qb,
                                                      const ushort* __restrict__ Ktl,
                                                      const ushort* __restrict__ Vtl,
                                                      float* __restrict__ out) {
    __shared__ __align__(16) ushort Ks[32 * 384];             // 24 KB panel image
    __shared__ __align__(16) ushort Vts[2][384 * 32];         // 2 x 24 KB
    __shared__ __align__(16) ushort Pq[2][4 * 32 * 8];        // 2 x 2 KB
    __shared__ float Ltab[2][2][2][16];                       // [qg][h][qh][i16]
    int id = blockIdx.x;                                   // 512 = 16 qt * 4 slot * 8 xcd
    int xcd = id & 7, slot = (id >> 3) & 3, qt = id >> 5;
    int b = slot * 8 + xcd;                                // batch grouped per XCD
    int tid = threadIdx.x;
    int wave = tid >> 6, lane = tid & 63;
    int i16 = lane & 15, gq = lane >> 4;
    int qg = wave & 1, h = wave >> 1;
    int q0w = qt * 64 + qg * 32;

    // linear coalesced staging: chunk ii (1KB), lane*16B contiguous
    auto stage_K = [&](int tt) {
        const ushort* pan = Ktl + (size_t)(b * 32 + tt) * 12288;
#pragma unroll
        for (int r = 0; r < 6; ++r) {
            int ii = wave * 6 + r;
            const ushort* ga = pan + ii * 512 + lane * 8;
            __builtin_amdgcn_global_load_lds(
                (const __attribute__((address_space(1))) uint32_t*)ga,
                (__attribute__((address_space(3))) uint32_t*)((char*)Ks + ii * 1024), 16, 0, 0);
        }
    };
    auto stage_V = [&](int tt, int bi) {
        const ushort* pan = Vtl + (size_t)(b * 32 + tt) * 12288;
#pragma unroll
        for (int r = 0; r < 6; ++r) {
            int ii = wave * 6 + r;
            const ushort* ga = pan + ii * 512 + lane * 8;
            __builtin_amdgcn_global_load_lds(
                (const __attribute__((address_space(1))) uint32_t*)ga,
                (__attribute__((address_space(3))) uint32_t*)((char*)&Vts[bi][0] + ii * 1024), 16, 0, 0);
        }
    };

    stage_K(0);
    stage_V(0, 0);

    // Q fragments (B-operand): lane (gq,i16): Q[q0w + qh*16 + i16][kt*32+gq*8..+8]
    bf16x8 qf[12][2];
    const ushort* Qb0 = Qb + (size_t)(b * S_LEN + q0w + i16) * D_MODEL;
    const ushort* Qb1 = Qb + (size_t)(b * S_LEN + q0w + 16 + i16) * D_MODEL;
#pragma unroll
    for (int kt = 0; kt < 12; ++kt) {
        qf[kt][0] = *reinterpret_cast<const bf16x8*>(Qb0 + kt * 32 + gq * 8);
        qf[kt][1] = *reinterpret_cast<const bf16x8*>(Qb1 + kt * 32 + gq * 8);
    }

    f32x4 oc[12][2] = {};
    float lsum0 = 0.f, lsum1 = 0.f;
    const float sl2e = 0.05103103630798287f * 1.4426950408889634f;

    char* PqB = (char*)&Pq[qg][0];
    const int krow = (h * 16 + i16) * 768;                // K row byte
    const int ksw  = (i16 & 7) << 4;                      // K col XOR
    const int kgq  = gq * 16;
    const int vx   = (gq * 16) ^ (((i16 >> 1) & 3) << 4); // V col byte (XOR folded)

    for (int t = 0; t < NT; ++t) {
        // K(t) landed (my 6 oldest); V(t) still in flight. lgkm drain closes
        // the P/K WAR window before the barrier.
        asm volatile("s_waitcnt vmcnt(6) lgkmcnt(0)" ::: "memory");
        __builtin_amdgcn_s_barrier();                      // B1: K(t) ready block-wide
        __builtin_amdgcn_sched_barrier(0);

        // ---- QK: S[h*16..+16 j][32 q] ----
        const char* Kb = (const char*)Ks;
        f32x4 sacc0 = {}, sacc1 = {};
        __builtin_amdgcn_s_setprio(1);
#pragma unroll
        for (int kt = 0; kt < 12; ++kt) {
            bf16x8 kf = *reinterpret_cast<const bf16x8*>(
                Kb + krow + (((kt * 64) | kgq) ^ ksw));
            sacc0 = MFMA16(kf, qf[kt][0], sacc0);
            sacc1 = MFMA16(kf, qf[kt][1], sacc1);
        }
        __builtin_amdgcn_s_setprio(0);

        // ---- p = exp2(s*scale*log2e) (drop-max), accumulate l, write P ----
        float p00 = exp2f(sacc0[0] * sl2e), p01 = exp2f(sacc0[1] * sl2e);
        float p02 = exp2f(sacc0[2] * sl2e), p03 = exp2f(sacc0[3] * sl2e);
        float p10 = exp2f(sacc1[0] * sl2e), p11 = exp2f(sacc1[1] * sl2e);
        float p12 = exp2f(sacc1[2] * sl2e), p13 = exp2f(sacc1[3] * sl2e);
        lsum0 += (p00 + p01) + (p02 + p03);
        lsum1 += (p10 + p11) + (p12 + p13);
        {
            // P[j = h*16+gq*4+r][q = qh*16+i16] -> byte jc*512 + q*16 + jl*2
            int pw = (h * 2 + (gq >> 1)) * 512 + (gq & 1) * 8;
            uint2 w0; w0.x = pk2(p00, p01); w0.y = pk2(p02, p03);
            uint2 w1; w1.x = pk2(p10, p11); w1.y = pk2(p12, p13);
            *reinterpret_cast<uint2*>(PqB + pw + i16 * 16) = w0;
            *reinterpret_cast<uint2*>(PqB + pw + (16 + i16) * 16) = w1;
        }
        // P visible + V(t) landed (issued a full tile ago -> near-free drain)
        asm volatile("s_waitcnt vmcnt(0) lgkmcnt(0)" ::: "memory");
        __builtin_amdgcn_s_barrier();                      // B2
        __builtin_amdgcn_sched_barrier(0);
        if (t + 1 < NT) {                                  // prefetch: never drained mid-tile
            stage_K(t + 1);
            stage_V(t + 1, (t + 1) & 1);
        }

        // ---- PV: O[h*192..+192 c][32 q] += V-half . P ----
        bf16x8 pf0 = *reinterpret_cast<const bf16x8*>(PqB + gq * 512 + i16 * 16);
        bf16x8 pf1 = *reinterpret_cast<const bf16x8*>(PqB + gq * 512 + (16 + i16) * 16);
        const char* Vb = (const char*)&Vts[t & 1][0];
        __builtin_amdgcn_s_setprio(1);
#pragma unroll
        for (int ct = 0; ct < 12; ++ct) {
            bf16x8 vf = *reinterpret_cast<const bf16x8*>(
                Vb + (h * 12 + ct) * 1024 + i16 * 64 + vx);
            oc[ct][0] = MFMA16(vf, pf0, oc[ct][0]);
            oc[ct][1] = MFMA16(vf, pf1, oc[ct][1]);
        }
        __builtin_amdgcn_s_setprio(0);
    }

    // ---- l: reduce over gq (this wave's j-half), then cross-half via LDS ----
    lsum0 += __shfl_xor(lsum0, 16); lsum0 += __shfl_xor(lsum0, 32);
    lsum1 += __shfl_xor(lsum1, 16); lsum1 += __shfl_xor(lsum1, 32);
    __syncthreads();
    if (gq == 0) {
        Ltab[qg][h][0][i16] = lsum0;
        Ltab[qg][h][1][i16] = lsum1;
    }
    __syncthreads();
    float inv0 = 1.0f / (Ltab[qg][0][0][i16] + Ltab[qg][1][0][i16]);
    float inv1 = 1.0f / (Ltab[qg][0][1][i16] + Ltab[qg][1][1][i16]);

    // ---- store O: c = h*192 + ct*16 + gq*4 + r, q = q0w + qh*16 + i16 ----
    float* obase = out + (size_t)b * D_MODEL * S_LEN + q0w + i16;
#pragma unroll
    for (int ct = 0; ct < 12; ++ct)
#pragma unroll
        for (int r = 0; r < 4; ++r) {
            int c = h * 192 + ct * 16 + gq * 4 + r;
            obase[(size_t)c * S_LEN] = oc[ct][0][r] * inv0;
            obase[(size_t)c * S_LEN + 16] = oc[ct][1][r] * inv1;
        }
}

extern "C" void kernel_launch(void* const* d_in, const int* in_sizes, int n_in,
                              void* d_out, int out_size, void* d_ws, size_t ws_size,
                              hipStream_t stream) {
    const float* x    = (const float*)d_in[0];
    const float* W    = (const float*)d_in[1];
    const float* bias = (const float*)d_in[2];
    float* out = (float*)d_out;

    char* ws = (char*)d_ws;
    ushort* A_bf = (ushort*)(ws);                // 25,165,824
    ushort* Wt   = (ushort*)(ws + 25165824);     //    884,736
    float*  peT  = (float*)(ws + 26050560);      //  1,572,864
    ushort* Qb   = (ushort*)(ws + 27623424);     // 25,165,824
    ushort* Ktl  = (ushort*)(ws + 52789248);     // 25,165,824
    ushort* Vtl  = (ushort*)(ws + 77955072);     // 25,165,824  (total 103,120,896)

    pe_kernel<<<1536, 256, 0, stream>>>(peT);
    wt_kernel<<<dim3(36, 12), dim3(32, 8), 0, stream>>>(W, Wt);
    astage_kernel<<<dim3(32, 12, 32), dim3(32, 8), 0, stream>>>(x, peT, A_bf);
    qkv_gemm<<<2304, 256, 0, stream>>>(A_bf, Wt, bias, Qb, Ktl, Vtl);
    attn_kernel<<<512, 256, 0, stream>>>(Qb, Ktl, Vtl, out);
}